// Round 7
// baseline (367.013 us; speedup 1.0000x reference)
//
#include <hip/hip_runtime.h>
#include <cmath>

// Problem constants (B=1): x (1,4,64,128,128) f32
#define Cc 64
#define Hh 128
#define Ww 128
#define HW_ 16384
#define THW_ 65536
#define CHW_ 1048576
#define NT 27

typedef unsigned short ushort_t;
typedef _Float16 f16x2 __attribute__((ext_vector_type(2)));
typedef _Float16 f16x8 __attribute__((ext_vector_type(8)));
typedef __fp16 fp16x2_alt __attribute__((ext_vector_type(2)));
typedef float floatx4 __attribute__((ext_vector_type(4)));
typedef unsigned uintx4 __attribute__((ext_vector_type(4)));

union U32H2 { unsigned u; f16x2 h; };
union B128 { uintx4 u; f16x8 h; };

static __device__ inline ushort_t f2h(float f) {
  union { _Float16 h; ushort_t u; } v;
  v.h = (_Float16)f;
  return v.u;
}

static __device__ inline unsigned pk2(float a) {
  union { fp16x2_alt h; unsigned u; } v;
  v.h = __builtin_amdgcn_cvt_pkrtz(a, a);
  return v.u;
}

#if defined(__has_builtin)
#if __has_builtin(__builtin_amdgcn_make_buffer_rsrc) && __has_builtin(__builtin_amdgcn_raw_buffer_load_b128)
#define USE_BUF 1
#endif
#endif
#ifndef USE_BUF
#define USE_BUF 0
#endif

struct XtBuf {
#if USE_BUF
  __amdgpu_buffer_rsrc_t r;
#else
  const char* p;
#endif
};

static __device__ inline XtBuf mkbuf(const ushort_t* xt) {
  XtBuf b;
#if USE_BUF
  b.r = __builtin_amdgcn_make_buffer_rsrc((void*)xt, (short)0, 8388608, 0x00020000);
#else
  b.p = (const char*)xt;
#endif
  return b;
}

// 16B load; voff must be a VALID clamped offset. If !ok, returns zeros
// (buffer path: OOB voff -> HW zero-fill; pointer path: select).
static __device__ inline uintx4 xload16m(const XtBuf& b, unsigned voff, bool ok) {
#if USE_BUF
  unsigned vo = ok ? voff : 0x40000000u;
  auto r = __builtin_amdgcn_raw_buffer_load_b128(b.r, (int)vo, 0, 0);
  uintx4 v;
  __builtin_memcpy(&v, &r, 16);
  return v;
#else
  uintx4 z = {0u, 0u, 0u, 0u};
  return ok ? *(const uintx4*)(b.p + voff) : z;
#endif
}

static __device__ inline uintx4 xload16(const XtBuf& b, unsigned voff) {
#if USE_BUF
  auto r = __builtin_amdgcn_raw_buffer_load_b128(b.r, (int)voff, 0, 0);
  uintx4 v;
  __builtin_memcpy(&v, &r, 16);
  return v;
#else
  return *(const uintx4*)(b.p + voff);
#endif
}

// ws layout (floats):
//   off    : [0, 5308416)           81 * 65536 f32
//   xt     : [5308416, +2097152)    x -> [t][h][w][c] f16 (4194304 ushorts)
//   wfrag  : [7405568, +55296)      deform weight B-frags, 110592 f16
//   w2frag : [7460864, +82944)      offconv weight B-frags, 165888 f16

__global__ __launch_bounds__(256) void prep(
    const float* __restrict__ offset_w,
    const float* __restrict__ weight,
    ushort_t* __restrict__ w2frag,
    ushort_t* __restrict__ wfrag)
{
  int e = blockIdx.x * 256 + threadIdx.x;
  if (e < 165888) {   // offconv: 27 taps x 6 oc-tiles x 2 khalf x 64 lanes x 8
    int j = e & 7, ln = (e >> 3) & 63, kh2 = (e >> 9) & 1, r = e >> 10;
    int ot = r % 6, k = r / 6;
    int oc = ot * 16 + (ln & 15);
    int c  = kh2 * 32 + (ln >> 4) * 8 + j;
    float v = (oc < 81) ? offset_w[(oc * 64 + c) * 27 + k] : 0.f;
    w2frag[e] = f2h(v);
  }
  if (e < 110592) {   // deform: 27 taps x 4 oc-tiles x 2 khalf x 64 lanes x 8
    int j = e & 7, ln = (e >> 3) & 63, kh2 = (e >> 9) & 1, r = e >> 10;
    int ot = r & 3, k = r >> 2;
    int o = ot * 16 + (ln & 15);
    int c = kh2 * 32 + (ln >> 4) * 8 + j;
    wfrag[e] = f2h(weight[(o * 64 + c) * 27 + k]);
  }
}

__global__ __launch_bounds__(256) void transpose_x(
    const float* __restrict__ x, ushort_t* __restrict__ xt)
{
  __shared__ float tile[64][65];
  int b = blockIdx.x;
  int wblk = b & 1;
  int th = b >> 1;
  int h = th & 127;
  int t = th >> 7;
  int w0 = wblk * 64;
  int lane = threadIdx.x & 63;
  int quad = threadIdx.x >> 6;
  #pragma unroll
  for (int cc = 0; cc < 16; ++cc) {
    int c = cc * 4 + quad;
    tile[c][lane] = x[t * CHW_ + c * HW_ + h * Ww + w0 + lane];
  }
  __syncthreads();
  #pragma unroll
  for (int ww = 0; ww < 16; ++ww) {
    int w = ww * 4 + quad;
    xt[(size_t)(t * HW_ + h * Ww + w0 + w) * 64 + lane] = f2h(tile[lane][w]);
  }
}

// Offset conv as MFMA GEMM, A-frags loaded DIRECTLY from global xt.
// Block = 64 pos, 4 waves, wave owns 16 pos x 96 oc. No LDS in tap loop.
// OOB zero-fill via buffer num_records bounds check.
__global__ __launch_bounds__(256, 4) void offconv(
    const ushort_t* __restrict__ xt,
    const ushort_t* __restrict__ w2frag,
    const float* __restrict__ ob,
    float* __restrict__ off)
{
  __shared__ float Dbuf[96 * 65];   // epilogue only (24960 B)
  int lane = threadIdx.x & 63;
  int wavei = __builtin_amdgcn_readfirstlane(threadIdx.x >> 6);
  int quad = lane >> 4;
  int m16 = lane & 15;
  int p0 = blockIdx.x * 64;
  int t = p0 >> 14;
  int h = (p0 >> 7) & 127;
  int w0 = p0 & 127;
  XtBuf xb = mkbuf(xt);

  floatx4 acc[6];
  #pragma unroll
  for (int i = 0; i < 6; ++i) acc[i] = (floatx4){0.f, 0.f, 0.f, 0.f};

  #pragma unroll 3
  for (int k = 0; k < NT; ++k) {
    int kt = k / 9, kh = (k / 3) % 3, kw = k % 3;
    int ts = t + kt - 1, hs = h + kh - 1;
    bool rowok = ((unsigned)ts < 4u) && ((unsigned)hs < 128u);
    int tsc = min(max(ts, 0), 3);
    int hsc = min(max(hs, 0), 127);
    int wc = w0 + wavei * 16 + m16 + kw - 1;
    bool ok = rowok && ((unsigned)wc < 128u);
    int wcc = min(max(wc, 0), 127);
    unsigned vo = ((unsigned)(tsc * HW_ + hsc * Ww + wcc) << 7) + (unsigned)(quad * 16);
    B128 a0, a1;
    a0.u = xload16m(xb, vo, ok);        // A[m16][quad*8 + j], ch 0..31
    a1.u = xload16m(xb, vo + 64, ok);   // ch 32..63
    #pragma unroll
    for (int ot = 0; ot < 6; ++ot) {
      const ushort_t* wb = w2frag + (size_t)((k * 6 + ot) * 2) * 512 + lane * 8;
      f16x8 b0 = *(const f16x8*)(wb);
      f16x8 b1 = *(const f16x8*)(wb + 512);
      acc[ot] = __builtin_amdgcn_mfma_f32_16x16x32_f16(a0.h, b0, acc[ot], 0, 0, 0);
      acc[ot] = __builtin_amdgcn_mfma_f32_16x16x32_f16(a1.h, b1, acc[ot], 0, 0, 0);
    }
  }
  #pragma unroll
  for (int ot = 0; ot < 6; ++ot)
    #pragma unroll
    for (int r = 0; r < 4; ++r)
      Dbuf[(ot * 16 + m16) * 65 + wavei * 16 + quad * 4 + r] = acc[ot][r];
  __syncthreads();
  for (int i = threadIdx.x; i < 81 * 64; i += 256) {
    int oc = i >> 6, p = i & 63;
    off[(size_t)oc * THW_ + p0 + p] = Dbuf[oc * 65 + p] + ob[oc];
  }
}

// Deformable sample + MFMA. Lane (m16=pos, quad=ch-oct round base) computes
// ALL 8 corners of its own position (meta 4x redundant across quads) and
// gathers dwordx4 (8 ch) per corner; interpolated result IS the A-fragment.
// Zero LDS, zero barriers in the tap loop.
__global__ __launch_bounds__(256, 4) void deform(
    const float* __restrict__ x,
    const ushort_t* __restrict__ xt,
    const float* __restrict__ off,
    const ushort_t* __restrict__ wfrag,
    const float* __restrict__ gamma,
    float* __restrict__ out)
{
  __shared__ float Dbuf[64 * 65];   // epilogue only (16640 B)
  int lane = threadIdx.x & 63;
  int wavei = __builtin_amdgcn_readfirstlane(threadIdx.x >> 6);
  int quad = lane >> 4;
  int m16 = lane & 15;
  int p0 = blockIdx.x * 64;
  int t = p0 >> 14;
  int h = (p0 >> 7) & 127;
  int w0 = p0 & 127;
  XtBuf xb = mkbuf(xt);

  floatx4 acc[4];
  #pragma unroll
  for (int i = 0; i < 4; ++i) acc[i] = (floatx4){0.f, 0.f, 0.f, 0.f};

  int pl = wavei * 16 + m16;
  int pm = p0 + pl;
  const float* offT = off + pm;

  float dt_c = offT[(size_t)(0 * NT + 0) * THW_];
  float dh_c = offT[(size_t)(1 * NT + 0) * THW_];
  float dw_c = offT[(size_t)(2 * NT + 0) * THW_];

  #pragma unroll 1
  for (int k = 0; k < NT; ++k) {
    int kn = (k + 1 < NT) ? k + 1 : NT - 1;
    float dt_n = offT[(size_t)(0 * NT + kn) * THW_];
    float dh_n = offT[(size_t)(1 * NT + kn) * THW_];
    float dw_n = offT[(size_t)(2 * NT + kn) * THW_];

    int kt = k / 9, kh = (k / 3) % 3, kw = k % 3;
    // --- meta: all 8 corners of position pl (duplicated across quads)
    float tf = (float)(t + kt - 1) + dt_c;
    float hf = (float)(h + kh - 1) + dh_c;
    float wf = (float)(w0 + pl + kw - 1) + dw_c;
    float tF = floorf(tf), hF = floorf(hf), wF = floorf(wf);
    float lt = tf - tF, lh_ = hf - hF, lw_ = wf - wF;
    int t0 = (int)tF, h0 = (int)hF, wq_ = (int)wF;
    float wtv[2], whv[2], wwv[2];
    int tiv[2], hiv[2], wiv[2];
    #pragma unroll
    for (int a = 0; a < 2; ++a) {
      int ti = t0 + a;
      wtv[a] = (a ? lt : 1.f - lt) * (((unsigned)ti < 4u) ? 1.f : 0.f);
      tiv[a] = min(max(ti, 0), 3);
      int hi = h0 + a;
      whv[a] = (a ? lh_ : 1.f - lh_) * (((unsigned)hi < 128u) ? 1.f : 0.f);
      hiv[a] = min(max(hi, 0), 127);
      int wi = wq_ + a;
      wwv[a] = (a ? lw_ : 1.f - lw_) * (((unsigned)wi < 128u) ? 1.f : 0.f);
      wiv[a] = min(max(wi, 0), 127);
    }
    unsigned vo[8], wk[8];
    #pragma unroll
    for (int a = 0; a < 2; ++a)
      #pragma unroll
      for (int b = 0; b < 2; ++b) {
        int rowb = tiv[a] * HW_ + hiv[b] * Ww;
        float rw = wtv[a] * whv[b];
        #pragma unroll
        for (int c = 0; c < 2; ++c) {
          int idx = (a * 2 + b) * 2 + c;
          vo[idx] = ((unsigned)(rowb + wiv[c]) << 7) + (unsigned)(quad * 16);
          wk[idx] = pk2(rw * wwv[c]);
        }
      }
    // --- gather round 0 (channels quad*8 .. +7)
    uintx4 d0[8];
    #pragma unroll
    for (int c = 0; c < 8; ++c) d0[c] = xload16(xb, vo[c]);
    // --- gather round 1 (channels 32+quad*8 .. +7)
    uintx4 d1[8];
    #pragma unroll
    for (int c = 0; c < 8; ++c) d1[c] = xload16(xb, vo[c] + 64);
    B128 a0, a1;
    {
      U32H2 z; z.u = 0;
      f16x2 s[4] = {z.h, z.h, z.h, z.h};
      #pragma unroll
      for (int c = 0; c < 8; ++c) {
        U32H2 wu; wu.u = wk[c];
        #pragma unroll
        for (int q = 0; q < 4; ++q) {
          U32H2 du; du.u = d0[c][q];
          s[q] += wu.h * du.h;
        }
      }
      U32H2 r0, r1, r2, r3;
      r0.h = s[0]; r1.h = s[1]; r2.h = s[2]; r3.h = s[3];
      a0.u = (uintx4){r0.u, r1.u, r2.u, r3.u};
    }
    {
      U32H2 z; z.u = 0;
      f16x2 s[4] = {z.h, z.h, z.h, z.h};
      #pragma unroll
      for (int c = 0; c < 8; ++c) {
        U32H2 wu; wu.u = wk[c];
        #pragma unroll
        for (int q = 0; q < 4; ++q) {
          U32H2 du; du.u = d1[c][q];
          s[q] += wu.h * du.h;
        }
      }
      U32H2 r0, r1, r2, r3;
      r0.h = s[0]; r1.h = s[1]; r2.h = s[2]; r3.h = s[3];
      a1.u = (uintx4){r0.u, r1.u, r2.u, r3.u};
    }
    // --- MFMA: 4 oc-tiles x 2 khalf
    #pragma unroll
    for (int ot = 0; ot < 4; ++ot) {
      const ushort_t* wb = wfrag + (size_t)((k * 4 + ot) * 2) * 512 + lane * 8;
      f16x8 b0 = *(const f16x8*)(wb);
      f16x8 b1 = *(const f16x8*)(wb + 512);
      acc[ot] = __builtin_amdgcn_mfma_f32_16x16x32_f16(a0.h, b0, acc[ot], 0, 0, 0);
      acc[ot] = __builtin_amdgcn_mfma_f32_16x16x32_f16(a1.h, b1, acc[ot], 0, 0, 0);
    }
    dt_c = dt_n; dh_c = dh_n; dw_c = dw_n;
  }
  #pragma unroll
  for (int ot = 0; ot < 4; ++ot)
    #pragma unroll
    for (int r = 0; r < 4; ++r)
      Dbuf[(ot * 16 + m16) * 65 + wavei * 16 + quad * 4 + r] = acc[ot][r];
  __syncthreads();
  float g = gamma[0];
  for (int i = threadIdx.x; i < 64 * 64; i += 256) {
    int oc = i >> 6, p = i & 63;
    size_t oi = (size_t)t * CHW_ + (size_t)oc * HW_ + (size_t)h * Ww + w0 + p;
    out[oi] = fmaf(g, Dbuf[oc * 65 + p], x[oi]);
  }
}

extern "C" void kernel_launch(void* const* d_in, const int* in_sizes, int n_in,
                              void* d_out, int out_size, void* d_ws, size_t ws_size,
                              hipStream_t stream) {
  (void)in_sizes; (void)n_in; (void)out_size; (void)ws_size;
  const float* x        = (const float*)d_in[0];
  const float* offset_w = (const float*)d_in[1];
  const float* offset_b = (const float*)d_in[2];
  const float* weight   = (const float*)d_in[3];
  const float* gamma    = (const float*)d_in[4];
  float* out = (float*)d_out;
  float* wsf = (float*)d_ws;
  float*    off    = wsf;                               // 5308416 f32
  ushort_t* xt     = (ushort_t*)(wsf + 5308416);        // 4194304 f16
  ushort_t* wfrag  = (ushort_t*)(wsf + 7405568);        // 110592 f16
  ushort_t* w2frag = (ushort_t*)(wsf + 7460864);        // 165888 f16

  hipLaunchKernelGGL(prep, dim3(648), dim3(256), 0, stream,
                     offset_w, weight, w2frag, wfrag);
  hipLaunchKernelGGL(transpose_x, dim3(1024), dim3(256), 0, stream, x, xt);
  hipLaunchKernelGGL(offconv, dim3(1024), dim3(256), 0, stream,
                     xt, w2frag, offset_b, off);
  hipLaunchKernelGGL(deform, dim3(1024), dim3(256), 0, stream,
                     x, xt, off, wfrag, gamma, out);
}

// Round 8
// 354.704 us; speedup vs baseline: 1.0347x; 1.0347x over previous
//
#include <hip/hip_runtime.h>
#include <cmath>

// Problem constants (B=1): x (1,4,64,128,128) f32
#define Cc 64
#define Hh 128
#define Ww 128
#define HW_ 16384
#define THW_ 65536
#define CHW_ 1048576
#define NT 27

typedef unsigned short ushort_t;
typedef _Float16 f16x2 __attribute__((ext_vector_type(2)));
typedef _Float16 f16x8 __attribute__((ext_vector_type(8)));
typedef __fp16 fp16x2_alt __attribute__((ext_vector_type(2)));
typedef float floatx4 __attribute__((ext_vector_type(4)));
typedef unsigned uintx4 __attribute__((ext_vector_type(4)));

union U32H2 { unsigned u; f16x2 h; };
union B128 { uintx4 u; f16x8 h; };

// Pin occupancy to exactly 4 waves/EU: gives the register allocator the full
// 128-VGPR budget so gather batches stay in flight (R7's 32-VGPR collapse).
#if defined(__has_attribute)
#if __has_attribute(amdgpu_waves_per_eu)
#define WPEU4 __attribute__((amdgpu_waves_per_eu(4, 4)))
#endif
#endif
#ifndef WPEU4
#define WPEU4
#endif

static __device__ inline ushort_t f2h(float f) {
  union { _Float16 h; ushort_t u; } v;
  v.h = (_Float16)f;
  return v.u;
}

static __device__ inline unsigned pk2(float a) {
  union { fp16x2_alt h; unsigned u; } v;
  v.h = __builtin_amdgcn_cvt_pkrtz(a, a);
  return v.u;
}

#if defined(__has_builtin)
#if __has_builtin(__builtin_amdgcn_make_buffer_rsrc) && __has_builtin(__builtin_amdgcn_raw_buffer_load_b128)
#define USE_BUF 1
#endif
#endif
#ifndef USE_BUF
#define USE_BUF 0
#endif

struct XtBuf {
#if USE_BUF
  __amdgpu_buffer_rsrc_t r;
#else
  const char* p;
#endif
};

static __device__ inline XtBuf mkbuf(const ushort_t* xt) {
  XtBuf b;
#if USE_BUF
  b.r = __builtin_amdgcn_make_buffer_rsrc((void*)xt, (short)0, 8388608, 0x00020000);
#else
  b.p = (const char*)xt;
#endif
  return b;
}

// 16B load; voff must be a VALID clamped offset. If !ok, returns zeros
// (buffer path: OOB voff -> HW zero-fill; pointer path: select).
static __device__ inline uintx4 xload16m(const XtBuf& b, unsigned voff, bool ok) {
#if USE_BUF
  unsigned vo = ok ? voff : 0x40000000u;
  auto r = __builtin_amdgcn_raw_buffer_load_b128(b.r, (int)vo, 0, 0);
  uintx4 v;
  __builtin_memcpy(&v, &r, 16);
  return v;
#else
  uintx4 z = {0u, 0u, 0u, 0u};
  return ok ? *(const uintx4*)(b.p + voff) : z;
#endif
}

static __device__ inline uintx4 xload16(const XtBuf& b, unsigned voff) {
#if USE_BUF
  auto r = __builtin_amdgcn_raw_buffer_load_b128(b.r, (int)voff, 0, 0);
  uintx4 v;
  __builtin_memcpy(&v, &r, 16);
  return v;
#else
  return *(const uintx4*)(b.p + voff);
#endif
}

// ws layout (floats):
//   off    : [0, 5308416)           81 * 65536 f32
//   xt     : [5308416, +2097152)    x -> [t][h][w][c] f16 (4194304 ushorts)
//   wfrag  : [7405568, +55296)      deform weight B-frags, 110592 f16
//   w2frag : [7460864, +82944)      offconv weight B-frags, 165888 f16

__global__ __launch_bounds__(256) void prep(
    const float* __restrict__ offset_w,
    const float* __restrict__ weight,
    ushort_t* __restrict__ w2frag,
    ushort_t* __restrict__ wfrag)
{
  int e = blockIdx.x * 256 + threadIdx.x;
  if (e < 165888) {   // offconv: 27 taps x 6 oc-tiles x 2 khalf x 64 lanes x 8
    int j = e & 7, ln = (e >> 3) & 63, kh2 = (e >> 9) & 1, r = e >> 10;
    int ot = r % 6, k = r / 6;
    int oc = ot * 16 + (ln & 15);
    int c  = kh2 * 32 + (ln >> 4) * 8 + j;
    float v = (oc < 81) ? offset_w[(oc * 64 + c) * 27 + k] : 0.f;
    w2frag[e] = f2h(v);
  }
  if (e < 110592) {   // deform: 27 taps x 4 oc-tiles x 2 khalf x 64 lanes x 8
    int j = e & 7, ln = (e >> 3) & 63, kh2 = (e >> 9) & 1, r = e >> 10;
    int ot = r & 3, k = r >> 2;
    int o = ot * 16 + (ln & 15);
    int c = kh2 * 32 + (ln >> 4) * 8 + j;
    wfrag[e] = f2h(weight[(o * 64 + c) * 27 + k]);
  }
}

__global__ __launch_bounds__(256) void transpose_x(
    const float* __restrict__ x, ushort_t* __restrict__ xt)
{
  __shared__ float tile[64][65];
  int b = blockIdx.x;
  int wblk = b & 1;
  int th = b >> 1;
  int h = th & 127;
  int t = th >> 7;
  int w0 = wblk * 64;
  int lane = threadIdx.x & 63;
  int quad = threadIdx.x >> 6;
  #pragma unroll
  for (int cc = 0; cc < 16; ++cc) {
    int c = cc * 4 + quad;
    tile[c][lane] = x[t * CHW_ + c * HW_ + h * Ww + w0 + lane];
  }
  __syncthreads();
  #pragma unroll
  for (int ww = 0; ww < 16; ++ww) {
    int w = ww * 4 + quad;
    xt[(size_t)(t * HW_ + h * Ww + w0 + w) * 64 + lane] = f2h(tile[lane][w]);
  }
}

// Offset conv as MFMA GEMM, A-frags loaded DIRECTLY from global xt.
// Block = 64 pos, 4 waves, wave owns 16 pos x 96 oc. No LDS in tap loop.
__global__ __launch_bounds__(256) WPEU4 void offconv(
    const ushort_t* __restrict__ xt,
    const ushort_t* __restrict__ w2frag,
    const float* __restrict__ ob,
    float* __restrict__ off)
{
  __shared__ float Dbuf[96 * 65];   // epilogue only (24960 B)
  int lane = threadIdx.x & 63;
  int wavei = __builtin_amdgcn_readfirstlane(threadIdx.x >> 6);
  int quad = lane >> 4;
  int m16 = lane & 15;
  int p0 = blockIdx.x * 64;
  int t = p0 >> 14;
  int h = (p0 >> 7) & 127;
  int w0 = p0 & 127;
  XtBuf xb = mkbuf(xt);

  floatx4 acc[6];
  #pragma unroll
  for (int i = 0; i < 6; ++i) acc[i] = (floatx4){0.f, 0.f, 0.f, 0.f};

  #pragma unroll 3
  for (int k = 0; k < NT; ++k) {
    int kt = k / 9, kh = (k / 3) % 3, kw = k % 3;
    int ts = t + kt - 1, hs = h + kh - 1;
    bool rowok = ((unsigned)ts < 4u) && ((unsigned)hs < 128u);
    int tsc = min(max(ts, 0), 3);
    int hsc = min(max(hs, 0), 127);
    int wc = w0 + wavei * 16 + m16 + kw - 1;
    bool ok = rowok && ((unsigned)wc < 128u);
    int wcc = min(max(wc, 0), 127);
    unsigned vo = ((unsigned)(tsc * HW_ + hsc * Ww + wcc) << 7) + (unsigned)(quad * 16);
    B128 a0, a1;
    a0.u = xload16m(xb, vo, ok);        // A[m16][quad*8 + j], ch 0..31
    a1.u = xload16m(xb, vo + 64, ok);   // ch 32..63
    #pragma unroll
    for (int ot = 0; ot < 6; ++ot) {
      const ushort_t* wb = w2frag + (size_t)((k * 6 + ot) * 2) * 512 + lane * 8;
      f16x8 b0 = *(const f16x8*)(wb);
      f16x8 b1 = *(const f16x8*)(wb + 512);
      acc[ot] = __builtin_amdgcn_mfma_f32_16x16x32_f16(a0.h, b0, acc[ot], 0, 0, 0);
      acc[ot] = __builtin_amdgcn_mfma_f32_16x16x32_f16(a1.h, b1, acc[ot], 0, 0, 0);
    }
  }
  #pragma unroll
  for (int ot = 0; ot < 6; ++ot)
    #pragma unroll
    for (int r = 0; r < 4; ++r)
      Dbuf[(ot * 16 + m16) * 65 + wavei * 16 + quad * 4 + r] = acc[ot][r];
  __syncthreads();
  for (int i = threadIdx.x; i < 81 * 64; i += 256) {
    int oc = i >> 6, p = i & 63;
    off[(size_t)oc * THW_ + p0 + p] = Dbuf[oc * 65 + p] + ob[oc];
  }
}

// Deformable sample + MFMA. Lane (m16=pos, quad=ch-oct) computes all 8 corners
// of its own position, gathers dwordx4 per corner (16 staged loads in flight),
// interpolates in-register; the result IS the A-fragment. Zero LDS / barriers
// in the tap loop.
__global__ __launch_bounds__(256) WPEU4 void deform(
    const float* __restrict__ x,
    const ushort_t* __restrict__ xt,
    const float* __restrict__ off,
    const ushort_t* __restrict__ wfrag,
    const float* __restrict__ gamma,
    float* __restrict__ out)
{
  __shared__ float Dbuf[64 * 65];   // epilogue only (16640 B)
  int lane = threadIdx.x & 63;
  int wavei = __builtin_amdgcn_readfirstlane(threadIdx.x >> 6);
  int quad = lane >> 4;
  int m16 = lane & 15;
  int p0 = blockIdx.x * 64;
  int t = p0 >> 14;
  int h = (p0 >> 7) & 127;
  int w0 = p0 & 127;
  XtBuf xb = mkbuf(xt);

  floatx4 acc[4];
  #pragma unroll
  for (int i = 0; i < 4; ++i) acc[i] = (floatx4){0.f, 0.f, 0.f, 0.f};

  int pl = wavei * 16 + m16;
  int pm = p0 + pl;
  const float* offT = off + pm;

  float dt_c = offT[(size_t)(0 * NT + 0) * THW_];
  float dh_c = offT[(size_t)(1 * NT + 0) * THW_];
  float dw_c = offT[(size_t)(2 * NT + 0) * THW_];

  #pragma unroll 1
  for (int k = 0; k < NT; ++k) {
    int kn = (k + 1 < NT) ? k + 1 : NT - 1;
    float dt_n = offT[(size_t)(0 * NT + kn) * THW_];
    float dh_n = offT[(size_t)(1 * NT + kn) * THW_];
    float dw_n = offT[(size_t)(2 * NT + kn) * THW_];

    int kt = k / 9, kh = (k / 3) % 3, kw = k % 3;
    // --- meta: all 8 corners of position pl (duplicated across quads)
    float tf = (float)(t + kt - 1) + dt_c;
    float hf = (float)(h + kh - 1) + dh_c;
    float wf = (float)(w0 + pl + kw - 1) + dw_c;
    float tF = floorf(tf), hF = floorf(hf), wF = floorf(wf);
    float lt = tf - tF, lh_ = hf - hF, lw_ = wf - wF;
    int t0 = (int)tF, h0 = (int)hF, wq_ = (int)wF;
    float wtv[2], whv[2], wwv[2];
    int tiv[2], hiv[2], wiv[2];
    #pragma unroll
    for (int a = 0; a < 2; ++a) {
      int ti = t0 + a;
      wtv[a] = (a ? lt : 1.f - lt) * (((unsigned)ti < 4u) ? 1.f : 0.f);
      tiv[a] = min(max(ti, 0), 3);
      int hi = h0 + a;
      whv[a] = (a ? lh_ : 1.f - lh_) * (((unsigned)hi < 128u) ? 1.f : 0.f);
      hiv[a] = min(max(hi, 0), 127);
      int wi = wq_ + a;
      wwv[a] = (a ? lw_ : 1.f - lw_) * (((unsigned)wi < 128u) ? 1.f : 0.f);
      wiv[a] = min(max(wi, 0), 127);
    }
    unsigned vo[8], wk[8];
    #pragma unroll
    for (int a = 0; a < 2; ++a)
      #pragma unroll
      for (int b = 0; b < 2; ++b) {
        int rowb = tiv[a] * HW_ + hiv[b] * Ww;
        float rw = wtv[a] * whv[b];
        #pragma unroll
        for (int c = 0; c < 2; ++c) {
          int idx = (a * 2 + b) * 2 + c;
          vo[idx] = ((unsigned)(rowb + wiv[c]) << 7) + (unsigned)(quad * 16);
          wk[idx] = pk2(rw * wwv[c]);
        }
      }
    // --- gather: all 16 loads issued before any consumption
    uintx4 d0[8], d1[8];
    #pragma unroll
    for (int c = 0; c < 8; ++c) d0[c] = xload16(xb, vo[c]);
    #pragma unroll
    for (int c = 0; c < 8; ++c) d1[c] = xload16(xb, vo[c] + 64);
    B128 a0, a1;
    {
      U32H2 z; z.u = 0;
      f16x2 s[4] = {z.h, z.h, z.h, z.h};
      #pragma unroll
      for (int c = 0; c < 8; ++c) {
        U32H2 wu; wu.u = wk[c];
        #pragma unroll
        for (int q = 0; q < 4; ++q) {
          U32H2 du; du.u = d0[c][q];
          s[q] += wu.h * du.h;
        }
      }
      U32H2 r0, r1, r2, r3;
      r0.h = s[0]; r1.h = s[1]; r2.h = s[2]; r3.h = s[3];
      a0.u = (uintx4){r0.u, r1.u, r2.u, r3.u};
    }
    {
      U32H2 z; z.u = 0;
      f16x2 s[4] = {z.h, z.h, z.h, z.h};
      #pragma unroll
      for (int c = 0; c < 8; ++c) {
        U32H2 wu; wu.u = wk[c];
        #pragma unroll
        for (int q = 0; q < 4; ++q) {
          U32H2 du; du.u = d1[c][q];
          s[q] += wu.h * du.h;
        }
      }
      U32H2 r0, r1, r2, r3;
      r0.h = s[0]; r1.h = s[1]; r2.h = s[2]; r3.h = s[3];
      a1.u = (uintx4){r0.u, r1.u, r2.u, r3.u};
    }
    // --- MFMA: 4 oc-tiles x 2 khalf
    #pragma unroll
    for (int ot = 0; ot < 4; ++ot) {
      const ushort_t* wb = wfrag + (size_t)((k * 4 + ot) * 2) * 512 + lane * 8;
      f16x8 b0 = *(const f16x8*)(wb);
      f16x8 b1 = *(const f16x8*)(wb + 512);
      acc[ot] = __builtin_amdgcn_mfma_f32_16x16x32_f16(a0.h, b0, acc[ot], 0, 0, 0);
      acc[ot] = __builtin_amdgcn_mfma_f32_16x16x32_f16(a1.h, b1, acc[ot], 0, 0, 0);
    }
    dt_c = dt_n; dh_c = dh_n; dw_c = dw_n;
  }
  #pragma unroll
  for (int ot = 0; ot < 4; ++ot)
    #pragma unroll
    for (int r = 0; r < 4; ++r)
      Dbuf[(ot * 16 + m16) * 65 + wavei * 16 + quad * 4 + r] = acc[ot][r];
  __syncthreads();
  float g = gamma[0];
  for (int i = threadIdx.x; i < 64 * 64; i += 256) {
    int oc = i >> 6, p = i & 63;
    size_t oi = (size_t)t * CHW_ + (size_t)oc * HW_ + (size_t)h * Ww + w0 + p;
    out[oi] = fmaf(g, Dbuf[oc * 65 + p], x[oi]);
  }
}

extern "C" void kernel_launch(void* const* d_in, const int* in_sizes, int n_in,
                              void* d_out, int out_size, void* d_ws, size_t ws_size,
                              hipStream_t stream) {
  (void)in_sizes; (void)n_in; (void)out_size; (void)ws_size;
  const float* x        = (const float*)d_in[0];
  const float* offset_w = (const float*)d_in[1];
  const float* offset_b = (const float*)d_in[2];
  const float* weight   = (const float*)d_in[3];
  const float* gamma    = (const float*)d_in[4];
  float* out = (float*)d_out;
  float* wsf = (float*)d_ws;
  float*    off    = wsf;                               // 5308416 f32
  ushort_t* xt     = (ushort_t*)(wsf + 5308416);        // 4194304 f16
  ushort_t* wfrag  = (ushort_t*)(wsf + 7405568);        // 110592 f16
  ushort_t* w2frag = (ushort_t*)(wsf + 7460864);        // 165888 f16

  hipLaunchKernelGGL(prep, dim3(648), dim3(256), 0, stream,
                     offset_w, weight, w2frag, wfrag);
  hipLaunchKernelGGL(transpose_x, dim3(1024), dim3(256), 0, stream, x, xt);
  hipLaunchKernelGGL(offconv, dim3(1024), dim3(256), 0, stream,
                     xt, w2frag, offset_b, off);
  hipLaunchKernelGGL(deform, dim3(1024), dim3(256), 0, stream,
                     x, xt, off, wfrag, gamma, out);
}